// Round 4
// baseline (2540.658 us; speedup 1.0000x reference)
//
#include <hip/hip_runtime.h>
#include <hip/hip_bf16.h>
#include <math.h>

#define NTOK 16384
#define DDIM 1024
#define HDIM 4096
#define NEXP 8

typedef __bf16 bf16_t;
typedef __bf16 bf16x8 __attribute__((ext_vector_type(8)));
typedef float f32x4 __attribute__((ext_vector_type(4)));

__device__ __forceinline__ void gld16(const bf16_t* g, bf16_t* l) {
    __builtin_amdgcn_global_load_lds(
        (const __attribute__((address_space(1))) void*)g,
        (__attribute__((address_space(3))) void*)l, 16, 0, 0);
}

// cheap erf: Abramowitz-Stegun 7.1.26, |err| < 1.5e-7 (<< bf16 ulp)
__device__ __forceinline__ float erf_fast(float u) {
    float au = fabsf(u);
    float tt = __builtin_amdgcn_rcpf(1.f + 0.3275911f * au);
    float poly = tt * (0.254829592f + tt * (-0.284496736f +
                 tt * (1.421413741f + tt * (-1.453152027f + tt * 1.061405429f))));
    float er = 1.f - poly * __expf(-au * au);
    return (u < 0.f) ? -er : er;
}

// ---------------- small utility kernels ----------------

__global__ void init_counts(int* counts) {
    if (threadIdx.x < NEXP) counts[threadIdx.x] = 0;
}

// ---------------- router: fp32 exact ----------------
__global__ void router_kernel(const float* __restrict__ x, const float* __restrict__ grad,
                              const float* __restrict__ rW, const float* __restrict__ rb,
                              float* __restrict__ probs, int* __restrict__ t2i,
                              float* __restrict__ t2g, int* __restrict__ counts) {
    const int lane = threadIdx.x & 63;
    const int n = blockIdx.x * 4 + (threadIdx.x >> 6);
    float acc[NEXP];
#pragma unroll
    for (int e = 0; e < NEXP; ++e) acc[e] = 0.f;
    const float* xr = x + (size_t)n * DDIM;
    for (int d = lane; d < DDIM; d += 64) {
        float xv = xr[d];
        const float* rr = rW + (size_t)d * NEXP;
#pragma unroll
        for (int e = 0; e < NEXP; ++e) acc[e] = fmaf(xv, rr[e], acc[e]);
    }
#pragma unroll
    for (int e = 0; e < NEXP; ++e) {
#pragma unroll
        for (int off = 32; off > 0; off >>= 1)
            acc[e] += __shfl_xor(acc[e], off, 64);
    }
    if (lane == 0) {
        float gv = grad[n];
        float p[NEXP];
        float mx = -1e30f;
#pragma unroll
        for (int e = 0; e < NEXP; ++e) {
            p[e] = acc[e] + gv * rW[(size_t)DDIM * NEXP + e] + rb[e];
            mx = fmaxf(mx, p[e]);
        }
        float s = 0.f;
#pragma unroll
        for (int e = 0; e < NEXP; ++e) { p[e] = expf(p[e] - mx); s += p[e]; }
        float inv = 1.f / s;
        int i1 = 0; float v1 = -1.f;
#pragma unroll
        for (int e = 0; e < NEXP; ++e) {
            p[e] *= inv;
            probs[(size_t)n * NEXP + e] = p[e];
            if (p[e] > v1) { v1 = p[e]; i1 = e; }   // strict > : lowest index wins ties
        }
        int i2 = 0; float v2 = -2.f;
#pragma unroll
        for (int e = 0; e < NEXP; ++e) {
            if (e != i1 && p[e] > v2) { v2 = p[e]; i2 = e; }
        }
        t2i[n * 2] = i1; t2i[n * 2 + 1] = i2;
        t2g[n * 2] = v1; t2g[n * 2 + 1] = v2;
        atomicAdd(&counts[i1], 1);
        atomicAdd(&counts[i2], 1);
    }
}

__global__ void offsets_kernel(const int* __restrict__ counts, int* __restrict__ offsets,
                               int* __restrict__ cursor) {
    if (threadIdx.x == 0) {
        int s = 0;
        for (int e = 0; e < NEXP; ++e) { offsets[e] = s; cursor[e] = s; s += counts[e]; }
    }
}

__global__ void build_lists(const int* __restrict__ t2i, const float* __restrict__ t2g,
                            int* __restrict__ cursor, int* __restrict__ tok,
                            float* __restrict__ gate, int* __restrict__ tslot) {
    int n = blockIdx.x * 256 + threadIdx.x;
#pragma unroll
    for (int k = 0; k < 2; ++k) {
        int e = t2i[n * 2 + k];
        int slot = atomicAdd(&cursor[e], 1);
        tok[slot] = n;
        gate[slot] = t2g[n * 2 + k];
        tslot[n * 2 + k] = slot;
    }
}

__global__ void gather_kernel(const float* __restrict__ x, const int* __restrict__ tok,
                              bf16_t* __restrict__ Xg) {
    const int r = blockIdx.x;
    const int t = threadIdx.x;
    const int token = tok[r];
    float4 v = ((const float4*)(x + (size_t)token * DDIM))[t];
    bf16_t o[4] = { (bf16_t)v.x, (bf16_t)v.y, (bf16_t)v.z, (bf16_t)v.w };
    *(uint2*)(Xg + (size_t)r * DDIM + t * 4) = *(const uint2*)o;
}

__global__ void transpose_cast(const float* __restrict__ in, bf16_t* __restrict__ out,
                               int R, int C) {
    __shared__ float tile[32][33];
    const size_t ebase = (size_t)blockIdx.z * R * C;
    const int c0 = blockIdx.x * 32, r0 = blockIdx.y * 32;
    const int tx = threadIdx.x, ty = threadIdx.y;  // (32, 8)
#pragma unroll
    for (int j = 0; j < 32; j += 8)
        tile[ty + j][tx] = in[ebase + (size_t)(r0 + ty + j) * C + c0 + tx];
    __syncthreads();
#pragma unroll
    for (int j = 0; j < 32; j += 8)
        out[ebase + (size_t)(c0 + ty + j) * R + r0 + tx] = (bf16_t)tile[tx][ty + j];
}

// combine: out[n] = Yg[slot1] + Yg[slot2]   (gate already applied in GEMM2 epilogue)
__global__ void combine_kernel(const float* __restrict__ Yg, const int* __restrict__ tslot,
                               float* __restrict__ out) {
    const int n = blockIdx.x, t = threadIdx.x;
    const int s1 = tslot[n * 2], s2 = tslot[n * 2 + 1];
    const float4 a = ((const float4*)(Yg + (size_t)s1 * DDIM))[t];
    const float4 b = ((const float4*)(Yg + (size_t)s2 * DDIM))[t];
    ((float4*)(out + (size_t)n * DDIM))[t] =
        make_float4(a.x + b.x, a.y + b.y, a.z + b.z, a.w + b.w);
}

// ---------------- MFMA GEMM: m97 128x128 structure, 4 blocks/CU ----------------
// C[M,N] = A[M,K] @ B^T[N,K], bf16 in / fp32 acc.  4 waves (2x2), 64x64 out each.
// Single-buffered 32KB LDS, simple stage->sync->mfma->sync loop: latency hiding
// comes from 4 INDEPENDENT blocks per CU (16 waves), not intra-block scheduling.
// Expert->XCD affinity: blockIdx.x = i*8 + e, so all of expert e's blocks land
// on XCD e (dispatch round-robins %8); i is m-fastest so co-resident blocks on
// an XCD share one B-panel (128xK = 256KB..1MB, L2-hot); A streams.
template <int K, int EPI>
__global__ __launch_bounds__(256, 4)
void moe_gemm(const bf16_t* __restrict__ A, const bf16_t* __restrict__ B,
              const float* __restrict__ bias, bf16_t* __restrict__ Hout,
              float* __restrict__ Yg, const int* __restrict__ counts,
              const int* __restrict__ offsets, const float* __restrict__ gate) {
    const int e = blockIdx.x & 7;
    const int i = blockIdx.x >> 3;
    const int mb = i & 127;          // m fastest within an XCD
    const int nb = i >> 7;
    const int count = counts[e];
    const int m0 = mb * 128;
    if (m0 >= count) return;         // uniform early-out, before any barrier
    const int n0 = nb * 128;
    const int off = offsets[e];

    const bf16_t* Ap = A + (size_t)(off + m0) * K;
    const bf16_t* Bp = B + (size_t)e * HDIM * DDIM + (size_t)n0 * K;
    const float*  bp = bias + (size_t)e * (EPI == 0 ? HDIM : DDIM) + n0;

    __shared__ __align__(16) bf16_t ldsA[128 * 64];
    __shared__ __align__(16) bf16_t ldsB[128 * 64];

    const int tid = threadIdx.x;
    const int lane = tid & 63;
    const int wv = tid >> 6;
    const int wm = (wv & 1) << 6;
    const int wn = (wv >> 1) << 6;

    f32x4 acc[4][4];
    const f32x4 zf = {0.f, 0.f, 0.f, 0.f};
#pragma unroll
    for (int a = 0; a < 4; ++a)
#pragma unroll
        for (int b = 0; b < 4; ++b) acc[a][b] = zf;

    // segment-major LDS layout: seg s = ks*128 + row; LDS bytes = s*16
    int sr[4], sk[4];
#pragma unroll
    for (int a = 0; a < 4; ++a) { int s = a * 256 + tid; sk[a] = s >> 7; sr[a] = s & 127; }

    for (int k0 = 0; k0 < K; k0 += 64) {
#pragma unroll
        for (int a = 0; a < 4; ++a) {
            gld16(Ap + (size_t)sr[a] * K + (k0 + sk[a] * 8), &ldsA[(size_t)(a * 256 + tid) * 8]);
            gld16(Bp + (size_t)sr[a] * K + (k0 + sk[a] * 8), &ldsB[(size_t)(a * 256 + tid) * 8]);
        }
        __syncthreads();
#pragma unroll
        for (int ki = 0; ki < 2; ++ki) {
            const int ks = ki * 4 + (lane >> 4);
            const int lm = lane & 15;
            bf16x8 af[4], bfr[4];
#pragma unroll
            for (int mt = 0; mt < 4; ++mt)
                af[mt] = *(const bf16x8*)&ldsA[(size_t)((ks * 128) + wm + mt * 16 + lm) * 8];
#pragma unroll
            for (int nt = 0; nt < 4; ++nt)
                bfr[nt] = *(const bf16x8*)&ldsB[(size_t)((ks * 128) + wn + nt * 16 + lm) * 8];
#pragma unroll
            for (int mt = 0; mt < 4; ++mt)
#pragma unroll
                for (int nt = 0; nt < 4; ++nt)
                    acc[mt][nt] = __builtin_amdgcn_mfma_f32_16x16x32_bf16(
                        af[mt], bfr[nt], acc[mt][nt], 0, 0, 0);
        }
        __syncthreads();
    }

    const int lm = lane & 15;
    const int lq = lane >> 4;
    if (EPI == 0) {
        // h = gelu(C + b1) -> packed Hbuf rows (guard: don't stomp next expert)
#pragma unroll
        for (int nt = 0; nt < 4; ++nt) {
            const int cc = wn + nt * 16 + lm;
            const float bv = bp[cc];
#pragma unroll
            for (int mt = 0; mt < 4; ++mt) {
#pragma unroll
                for (int r = 0; r < 4; ++r) {
                    const int row = m0 + wm + mt * 16 + lq * 4 + r;
                    if (row < count) {
                        float v = acc[mt][nt][r] + bv;
                        float er = erf_fast(v * 0.70710678118654752f);
                        Hout[((size_t)off + row) * HDIM + n0 + cc] =
                            (bf16_t)(0.5f * v * (1.f + er));
                    }
                }
            }
        }
    } else {
        // Yg[slot] = gate * (C + b2), fp32, no atomics
#pragma unroll
        for (int mt = 0; mt < 4; ++mt) {
#pragma unroll
            for (int r = 0; r < 4; ++r) {
                const int row = m0 + wm + mt * 16 + lq * 4 + r;
                if (row < count) {
                    const int slot = off + row;
                    const float g = gate[slot];
                    float* yrow = Yg + (size_t)slot * DDIM + n0;
#pragma unroll
                    for (int nt = 0; nt < 4; ++nt) {
                        const int cc = wn + nt * 16 + lm;
                        yrow[cc] = g * (acc[mt][nt][r] + bp[cc]);
                    }
                }
            }
        }
    }
}

// ---------------- launch ----------------

extern "C" void kernel_launch(void* const* d_in, const int* in_sizes, int n_in,
                              void* d_out, int out_size, void* d_ws, size_t ws_size,
                              hipStream_t stream) {
    const float* x    = (const float*)d_in[0];
    const float* grad = (const float*)d_in[1];
    const float* rW   = (const float*)d_in[2];
    const float* rb   = (const float*)d_in[3];
    const float* W1   = (const float*)d_in[4];
    const float* b1   = (const float*)d_in[5];
    const float* W2   = (const float*)d_in[6];
    const float* b2   = (const float*)d_in[7];
    float* out   = (float*)d_out;                 // [N][D]
    float* probs = out + (size_t)NTOK * DDIM;     // [N][E]

    char* base = (char*)d_ws;
    size_t p = 0;
    auto alloc = [&](size_t bytes) -> void* {
        void* r = base + p;
        p = (p + bytes + 255) & ~(size_t)255;
        return r;
    };

    int*    counts  = (int*)alloc(3 * NEXP * sizeof(int));
    int*    offsets = counts + NEXP;
    int*    cursor  = offsets + NEXP;
    int*    t2i   = (int*)alloc((size_t)NTOK * 2 * sizeof(int));
    float*  t2g   = (float*)alloc((size_t)NTOK * 2 * sizeof(float));
    int*    tok   = (int*)alloc((size_t)2 * NTOK * sizeof(int));
    float*  gate  = (float*)alloc((size_t)2 * NTOK * sizeof(float));
    int*    tslot = (int*)alloc((size_t)NTOK * 2 * sizeof(int));
    bf16_t* Xg   = (bf16_t*)alloc(((size_t)2 * NTOK + 256) * DDIM * sizeof(bf16_t));
    bf16_t* W1t  = (bf16_t*)alloc((size_t)NEXP * HDIM * DDIM * sizeof(bf16_t));
    bf16_t* W2t  = (bf16_t*)alloc((size_t)NEXP * HDIM * DDIM * sizeof(bf16_t));
    bf16_t* Hbuf = (bf16_t*)alloc(((size_t)2 * NTOK + 256) * HDIM * sizeof(bf16_t));
    // Yg (32768 x 1024 fp32 = 134.2MB) aliases Xg+W1t (134.7MB): both are dead once
    // GEMM1 has run; GEMM2 writes Yg, combine reads it. Stream order guarantees safety.
    float* Yg = (float*)Xg;

    hipLaunchKernelGGL(init_counts, dim3(1), dim3(64), 0, stream, counts);
    hipLaunchKernelGGL(router_kernel, dim3(NTOK / 4), dim3(256), 0, stream,
                       x, grad, rW, rb, probs, t2i, t2g, counts);
    hipLaunchKernelGGL(offsets_kernel, dim3(1), dim3(64), 0, stream, counts, offsets, cursor);
    hipLaunchKernelGGL(build_lists, dim3(NTOK / 256), dim3(256), 0, stream,
                       t2i, t2g, cursor, tok, gate, tslot);
    hipLaunchKernelGGL(gather_kernel, dim3(2 * NTOK), dim3(256), 0, stream, x, tok, Xg);
    hipLaunchKernelGGL(transpose_cast, dim3(HDIM / 32, DDIM / 32, NEXP), dim3(32, 8), 0, stream,
                       W1, W1t, DDIM, HDIM);
    hipLaunchKernelGGL(transpose_cast, dim3(DDIM / 32, HDIM / 32, NEXP), dim3(32, 8), 0, stream,
                       W2, W2t, HDIM, DDIM);

    // GEMM1: ragged [counts, 4096] = Xg @ W1t^T, gelu -> Hbuf (bf16, packed rows)
    // grid = (n-blocks per expert) * (m-blocks 128) * 8 experts, bid = i*8 + e
    hipLaunchKernelGGL((moe_gemm<DDIM, 0>), dim3((HDIM / 128) * 128 * NEXP), dim3(256), 0,
                       stream, Xg, W1t, b1, Hbuf, (float*)nullptr, counts, offsets, gate);
    // GEMM2: Yg[slot] = gate * (Hbuf @ W2t^T + b2)   (fp32, no atomics)
    hipLaunchKernelGGL((moe_gemm<HDIM, 1>), dim3((DDIM / 128) * 128 * NEXP), dim3(256), 0,
                       stream, Hbuf, W2t, b2, (bf16_t*)nullptr, Yg, counts, offsets, gate);
    hipLaunchKernelGGL(combine_kernel, dim3(NTOK), dim3(256), 0, stream, Yg, tslot, out);
}

// Round 5
// 1937.076 us; speedup vs baseline: 1.3116x; 1.3116x over previous
//
#include <hip/hip_runtime.h>
#include <hip/hip_bf16.h>
#include <math.h>

#define NTOK 16384
#define DDIM 1024
#define HDIM 4096
#define NEXP 8

typedef __bf16 bf16_t;
typedef __bf16 bf16x8 __attribute__((ext_vector_type(8)));
typedef float f32x4 __attribute__((ext_vector_type(4)));

__device__ __forceinline__ void gld16(const bf16_t* g, bf16_t* l) {
    __builtin_amdgcn_global_load_lds(
        (const __attribute__((address_space(1))) void*)g,
        (__attribute__((address_space(3))) void*)l, 16, 0, 0);
}

// stage one 128-row x 64-col bf16 half-tile (16KB) into LDS, segment-major:
// segment s = kg*128 + r  ->  lds bytes s*16.  2 gld16 per thread (512 thr).
__device__ __forceinline__ void stage_half(const bf16_t* __restrict__ g, int K, int kofs,
                                           bf16_t* l, int tid) {
#pragma unroll
    for (int c = 0; c < 2; ++c) {
        const int s = c * 512 + tid;
        const int kg = s >> 7, r = s & 127;
        gld16(g + (size_t)r * K + (kofs + kg * 8), l + (size_t)s * 8);
    }
}

// cheap erf: Abramowitz-Stegun 7.1.26, |err| < 1.5e-7 (<< bf16 ulp)
__device__ __forceinline__ float erf_fast(float u) {
    float au = fabsf(u);
    float tt = __builtin_amdgcn_rcpf(1.f + 0.3275911f * au);
    float poly = tt * (0.254829592f + tt * (-0.284496736f +
                 tt * (1.421413741f + tt * (-1.453152027f + tt * 1.061405429f))));
    float er = 1.f - poly * __expf(-au * au);
    return (u < 0.f) ? -er : er;
}

// ---------------- small utility kernels ----------------

__global__ void init_counts(int* counts) {
    if (threadIdx.x < NEXP) counts[threadIdx.x] = 0;
}

// ---------------- router: fp32 exact ----------------
__global__ void router_kernel(const float* __restrict__ x, const float* __restrict__ grad,
                              const float* __restrict__ rW, const float* __restrict__ rb,
                              float* __restrict__ probs, int* __restrict__ t2i,
                              float* __restrict__ t2g, int* __restrict__ counts) {
    const int lane = threadIdx.x & 63;
    const int n = blockIdx.x * 4 + (threadIdx.x >> 6);
    float acc[NEXP];
#pragma unroll
    for (int e = 0; e < NEXP; ++e) acc[e] = 0.f;
    const float* xr = x + (size_t)n * DDIM;
    for (int d = lane; d < DDIM; d += 64) {
        float xv = xr[d];
        const float* rr = rW + (size_t)d * NEXP;
#pragma unroll
        for (int e = 0; e < NEXP; ++e) acc[e] = fmaf(xv, rr[e], acc[e]);
    }
#pragma unroll
    for (int e = 0; e < NEXP; ++e) {
#pragma unroll
        for (int off = 32; off > 0; off >>= 1)
            acc[e] += __shfl_xor(acc[e], off, 64);
    }
    if (lane == 0) {
        float gv = grad[n];
        float p[NEXP];
        float mx = -1e30f;
#pragma unroll
        for (int e = 0; e < NEXP; ++e) {
            p[e] = acc[e] + gv * rW[(size_t)DDIM * NEXP + e] + rb[e];
            mx = fmaxf(mx, p[e]);
        }
        float s = 0.f;
#pragma unroll
        for (int e = 0; e < NEXP; ++e) { p[e] = expf(p[e] - mx); s += p[e]; }
        float inv = 1.f / s;
        int i1 = 0; float v1 = -1.f;
#pragma unroll
        for (int e = 0; e < NEXP; ++e) {
            p[e] *= inv;
            probs[(size_t)n * NEXP + e] = p[e];
            if (p[e] > v1) { v1 = p[e]; i1 = e; }   // strict > : lowest index wins ties
        }
        int i2 = 0; float v2 = -2.f;
#pragma unroll
        for (int e = 0; e < NEXP; ++e) {
            if (e != i1 && p[e] > v2) { v2 = p[e]; i2 = e; }
        }
        t2i[n * 2] = i1; t2i[n * 2 + 1] = i2;
        t2g[n * 2] = v1; t2g[n * 2 + 1] = v2;
        atomicAdd(&counts[i1], 1);
        atomicAdd(&counts[i2], 1);
    }
}

__global__ void offsets_kernel(const int* __restrict__ counts, int* __restrict__ offsets,
                               int* __restrict__ cursor) {
    if (threadIdx.x == 0) {
        int s = 0;
        for (int e = 0; e < NEXP; ++e) { offsets[e] = s; cursor[e] = s; s += counts[e]; }
    }
}

__global__ void build_lists(const int* __restrict__ t2i, const float* __restrict__ t2g,
                            int* __restrict__ cursor, int* __restrict__ tok,
                            float* __restrict__ gate, int* __restrict__ tslot) {
    int n = blockIdx.x * 256 + threadIdx.x;
#pragma unroll
    for (int k = 0; k < 2; ++k) {
        int e = t2i[n * 2 + k];
        int slot = atomicAdd(&cursor[e], 1);
        tok[slot] = n;
        gate[slot] = t2g[n * 2 + k];
        tslot[n * 2 + k] = slot;
    }
}

__global__ void gather_kernel(const float* __restrict__ x, const int* __restrict__ tok,
                              bf16_t* __restrict__ Xg) {
    const int r = blockIdx.x;
    const int t = threadIdx.x;
    const int token = tok[r];
    float4 v = ((const float4*)(x + (size_t)token * DDIM))[t];
    bf16_t o[4] = { (bf16_t)v.x, (bf16_t)v.y, (bf16_t)v.z, (bf16_t)v.w };
    *(uint2*)(Xg + (size_t)r * DDIM + t * 4) = *(const uint2*)o;
}

// fused W1+W2 transpose+cast: fp32 [R][C] -> bf16 [C][R], 64x64 tiles,
// float4 loads + uint4 (bf16x8) stores.  z<8: W1 expert z (R=D,C=H);
// z>=8: W2 expert z-8 (R=H,C=D).  Tiles per expert = (C/64)*(R/64) = 1024 both.
__global__ void transpose_cast2(const float* __restrict__ W1, const float* __restrict__ W2,
                                bf16_t* __restrict__ W1t, bf16_t* __restrict__ W2t) {
    __shared__ float tile[64][65];
    const int z = blockIdx.y;
    const float* in;
    bf16_t* out;
    int R, C;
    if (z < 8) { in = W1 + (size_t)z * DDIM * HDIM; out = W1t + (size_t)z * DDIM * HDIM;
                 R = DDIM; C = HDIM; }
    else       { in = W2 + (size_t)(z - 8) * DDIM * HDIM; out = W2t + (size_t)(z - 8) * DDIM * HDIM;
                 R = HDIM; C = DDIM; }
    const int ct = C >> 6;
    const int c0 = (blockIdx.x & (ct - 1)) << 6;    // ct is 64 or 16 (pow2)
    const int r0 = (blockIdx.x / ct) << 6;
    const int t = threadIdx.x;
    const int tc = t & 15, tr = t >> 4;
#pragma unroll
    for (int i = 0; i < 4; ++i) {
        const int rr = tr + i * 16;
        const float4 v = *(const float4*)&in[(size_t)(r0 + rr) * C + c0 + tc * 4];
        tile[rr][tc * 4 + 0] = v.x;
        tile[rr][tc * 4 + 1] = v.y;
        tile[rr][tc * 4 + 2] = v.z;
        tile[rr][tc * 4 + 3] = v.w;
    }
    __syncthreads();
    const int oc = t >> 2;                          // output row (= input col) 0..63
#pragma unroll
    for (int i = 0; i < 2; ++i) {
        const int rb = (t & 3) + i * 4;             // 8-elem chunk 0..7
        bf16_t o[8];
#pragma unroll
        for (int k = 0; k < 8; ++k) o[k] = (bf16_t)tile[rb * 8 + k][oc];
        *(uint4*)&out[(size_t)(c0 + oc) * R + r0 + rb * 8] = *(const uint4*)o;
    }
}

// combine: out[n] = Yg[slot1] + Yg[slot2]   (gate already applied in GEMM2 epilogue)
__global__ void combine_kernel(const float* __restrict__ Yg, const int* __restrict__ tslot,
                               float* __restrict__ out) {
    const int n = blockIdx.x, t = threadIdx.x;
    const int s1 = tslot[n * 2], s2 = tslot[n * 2 + 1];
    const float4 a = ((const float4*)(Yg + (size_t)s1 * DDIM))[t];
    const float4 b = ((const float4*)(Yg + (size_t)s2 * DDIM))[t];
    ((float4*)(out + (size_t)n * DDIM))[t] =
        make_float4(a.x + b.x, a.y + b.y, a.z + b.z, a.w + b.w);
}

// ---------------- 256x256 8-phase grouped MFMA GEMM (round-1 verbatim) ----------------
// C[M,N] = A[M,K] @ B^T[N,K], bf16 in / fp32 acc.  8 waves (2M x 4N), each 128x64 out.
// LDS: [buf(2)][mat(2)][half(2)] x 16KB = 128KB.  Raw s_barrier + counted vmcnt.
#define PHASE_SYNC() do { \
    __builtin_amdgcn_s_barrier(); \
    asm volatile("s_waitcnt lgkmcnt(0)" ::: "memory"); \
    __builtin_amdgcn_sched_barrier(0); \
    __builtin_amdgcn_s_setprio(1); \
} while (0)

#define PHASE_END() do { \
    __builtin_amdgcn_s_setprio(0); \
    __builtin_amdgcn_s_barrier(); \
} while (0)

#define MMA16(QA, QB) do { \
    _Pragma("unroll") \
    for (int mt = 0; mt < 4; ++mt) { \
        _Pragma("unroll") \
        for (int nt = 0; nt < 2; ++nt) { \
            _Pragma("unroll") \
            for (int ks = 0; ks < 2; ++ks) \
                acc[(QA) * 4 + mt][(QB) * 2 + nt] = \
                    __builtin_amdgcn_mfma_f32_16x16x32_bf16( \
                        aF[ks][mt], bF[ks][nt], acc[(QA) * 4 + mt][(QB) * 2 + nt], 0, 0, 0); \
        } \
    } \
} while (0)

template <int K, int EPI>
__global__ __launch_bounds__(512, 2)
void moe_gemm8(const bf16_t* __restrict__ A, const bf16_t* __restrict__ B,
               const float* __restrict__ bias, bf16_t* __restrict__ Hout,
               float* __restrict__ Yg, const int* __restrict__ counts,
               const int* __restrict__ offsets, const float* __restrict__ gate,
               int gx) {
    const int NT = K / 64;
    // XCD-bijective swizzle (nwg % 8 == 0): each XCD gets a contiguous chunk = one expert.
    const int nwg = gridDim.x;
    const int q8 = nwg >> 3;
    const int v = (blockIdx.x & 7) * q8 + (blockIdx.x >> 3);
    const int per_e = gx * 64;                  // 64 = max m-blocks (NTOK/256)
    const int e = v / per_e;
    const int rem = v - e * per_e;
    // within expert: 8y x 4x super-tiles (32 blocks = one XCD residency)
    const int xsc = gx >> 2;
    const int sup = rem >> 5, sub = rem & 31;
    const int ys = sup / xsc, xs = sup - ys * xsc;
    const int yb = ys * 8 + (sub >> 2), xb = xs * 4 + (sub & 3);

    const int count = counts[e];
    const int m0 = yb * 256;
    if (m0 >= count) return;
    const int n0 = xb * 256;
    const int off = offsets[e];

    const bf16_t* Ae = A + (size_t)(off + m0) * K;          // packed rows (both GEMMs)
    const bf16_t* Be = B + (size_t)e * HDIM * DDIM + (size_t)n0 * K;
    const bf16_t* Ae1 = Ae + (size_t)128 * K;
    const bf16_t* Be1 = Be + (size_t)128 * K;

    __shared__ __align__(16) bf16_t lds[2][2][2][8192];     // [buf][A/B][half][16KB]

    const int tid = threadIdx.x;
    const int lane = tid & 63;
    const int lm = lane & 15, hi = lane >> 4;
    const int wv = tid >> 6;
    const int wm16 = (wv >> 2) << 4;    // 0 / 16
    const int wn16 = (wv & 3) << 4;     // 0 / 16 / 32 / 48

    f32x4 acc[8][4];
    const f32x4 zf = {0.f, 0.f, 0.f, 0.f};
#pragma unroll
    for (int i = 0; i < 8; ++i)
#pragma unroll
        for (int j = 0; j < 4; ++j) acc[i][j] = zf;

    bf16x8 aF[2][4], bF[2][2];
    auto readA = [&](const bf16_t* Ab) {
#pragma unroll
        for (int mt = 0; mt < 4; ++mt)
#pragma unroll
            for (int ks = 0; ks < 2; ++ks)
                aF[ks][mt] = *(const bf16x8*)(Ab + (size_t)((ks * 4 + hi) * 128 +
                                                            mt * 32 + wm16 + lm) * 8);
    };
    auto readB = [&](const bf16_t* Bb) {
#pragma unroll
        for (int nt = 0; nt < 2; ++nt)
#pragma unroll
            for (int ks = 0; ks < 2; ++ks)
                bF[ks][nt] = *(const bf16x8*)(Bb + (size_t)((ks * 4 + hi) * 128 +
                                                            nt * 64 + wn16 + lm) * 8);
    };

    // prologue: tile0 fully + tile1's A-h0,B-h1; wait so tile0 resident, 2 half-tiles in flight
    stage_half(Ae,  K, 0, &lds[0][0][0][0], tid);
    stage_half(Ae1, K, 0, &lds[0][0][1][0], tid);
    stage_half(Be,  K, 0, &lds[0][1][0][0], tid);
    stage_half(Be1, K, 0, &lds[0][1][1][0], tid);
    const int k1p = (NT > 1 ? 1 : 0) * 64;
    stage_half(Ae,  K, k1p, &lds[1][0][0][0], tid);
    stage_half(Be1, K, k1p, &lds[1][1][1][0], tid);
    asm volatile("s_waitcnt vmcnt(4)" ::: "memory");
    __builtin_amdgcn_s_barrier();

    int cur = 0;
    for (int t = 0; t < NT; ++t, cur ^= 1) {
        const int nxt = cur ^ 1;
        const int k1 = ((t + 1 < NT) ? t + 1 : NT - 1) * 64;   // clamp: dead writes only
        const int k2 = ((t + 2 < NT) ? t + 2 : NT - 1) * 64;
        // ---- phase 0: quadrant (A-half0, B-half0)
        readA(&lds[cur][0][0][0]);
        readB(&lds[cur][1][0][0]);
        stage_half(Ae1, K, k1, &lds[nxt][0][1][0], tid);   // A-h1(t+1)
        stage_half(Be,  K, k1, &lds[nxt][1][0][0], tid);   // B-h0(t+1)
        PHASE_SYNC(); MMA16(0, 0); PHASE_END();
        // ---- phase 1: (A-half0, B-half1) — A regs reused
        readB(&lds[cur][1][1][0]);
        stage_half(Ae, K, k2, &lds[cur][0][0][0], tid);    // A-h0(t+2); slot dead since ph0
        PHASE_SYNC(); MMA16(0, 1); PHASE_END();
        // ---- phase 2: (A-half1, B-half1) — B regs reused
        readA(&lds[cur][0][1][0]);
        stage_half(Be1, K, k2, &lds[cur][1][1][0], tid);   // B-h1(t+2); slot dead since ph1
        PHASE_SYNC(); MMA16(1, 1); PHASE_END();
        // ---- phase 3: (A-half1, B-half0)
        readB(&lds[cur][1][0][0]);
        PHASE_SYNC(); MMA16(1, 0);
        __builtin_amdgcn_s_setprio(0);
        asm volatile("s_waitcnt vmcnt(4)" ::: "memory");   // t+1 fully resident; t+2 in flight
        __builtin_amdgcn_s_barrier();
    }

    // ---------------- epilogue ----------------
    if (EPI == 0) {
        const float* bp = bias + (size_t)e * HDIM + n0;
#pragma unroll
        for (int mt = 0; mt < 8; ++mt) {
#pragma unroll
            for (int r = 0; r < 4; ++r) {
                const int row = m0 + mt * 32 + wm16 + hi * 4 + r;
                if (row < count) {
                    bf16_t* hrow = Hout + (size_t)(off + row) * HDIM + n0;
#pragma unroll
                    for (int nt = 0; nt < 4; ++nt) {
                        const int cc = nt * 64 + wn16 + lm;
                        float vv = acc[mt][nt][r] + bp[cc];
                        float er = erf_fast(vv * 0.70710678118654752f);
                        hrow[cc] = (bf16_t)(0.5f * vv * (1.f + er));
                    }
                }
            }
        }
    } else {
        const float* bp = bias + (size_t)e * DDIM + n0;
#pragma unroll
        for (int mt = 0; mt < 8; ++mt) {
#pragma unroll
            for (int r = 0; r < 4; ++r) {
                const int row = m0 + mt * 32 + wm16 + hi * 4 + r;
                if (row < count) {
                    const int slot = off + row;
                    const float g = gate[slot];
                    float* yrow = Yg + (size_t)slot * DDIM + n0;
#pragma unroll
                    for (int nt = 0; nt < 4; ++nt) {
                        const int cc = nt * 64 + wn16 + lm;
                        yrow[cc] = g * (acc[mt][nt][r] + bp[cc]);
                    }
                }
            }
        }
    }
}

// ---------------- launch ----------------

extern "C" void kernel_launch(void* const* d_in, const int* in_sizes, int n_in,
                              void* d_out, int out_size, void* d_ws, size_t ws_size,
                              hipStream_t stream) {
    const float* x    = (const float*)d_in[0];
    const float* grad = (const float*)d_in[1];
    const float* rW   = (const float*)d_in[2];
    const float* rb   = (const float*)d_in[3];
    const float* W1   = (const float*)d_in[4];
    const float* b1   = (const float*)d_in[5];
    const float* W2   = (const float*)d_in[6];
    const float* b2   = (const float*)d_in[7];
    float* out   = (float*)d_out;                 // [N][D]
    float* probs = out + (size_t)NTOK * DDIM;     // [N][E]

    char* base = (char*)d_ws;
    size_t p = 0;
    auto alloc = [&](size_t bytes) -> void* {
        void* r = base + p;
        p = (p + bytes + 255) & ~(size_t)255;
        return r;
    };

    int*    counts  = (int*)alloc(3 * NEXP * sizeof(int));
    int*    offsets = counts + NEXP;
    int*    cursor  = offsets + NEXP;
    int*    t2i   = (int*)alloc((size_t)NTOK * 2 * sizeof(int));
    float*  t2g   = (float*)alloc((size_t)NTOK * 2 * sizeof(float));
    int*    tok   = (int*)alloc((size_t)2 * NTOK * sizeof(int));
    float*  gate  = (float*)alloc((size_t)2 * NTOK * sizeof(float));
    int*    tslot = (int*)alloc((size_t)NTOK * 2 * sizeof(int));
    bf16_t* Xg   = (bf16_t*)alloc(((size_t)2 * NTOK + 256) * DDIM * sizeof(bf16_t));
    bf16_t* W1t  = (bf16_t*)alloc((size_t)NEXP * HDIM * DDIM * sizeof(bf16_t));
    bf16_t* W2t  = (bf16_t*)alloc((size_t)NEXP * HDIM * DDIM * sizeof(bf16_t));
    bf16_t* Hbuf = (bf16_t*)alloc(((size_t)2 * NTOK + 256) * HDIM * sizeof(bf16_t));
    // Yg (32768 x 1024 fp32 = 134.2MB) aliases Xg+W1t (134.7MB): both are dead once
    // GEMM1 has run; GEMM2 writes Yg, combine reads it. Stream order guarantees safety.
    float* Yg = (float*)Xg;

    hipLaunchKernelGGL(init_counts, dim3(1), dim3(64), 0, stream, counts);
    hipLaunchKernelGGL(router_kernel, dim3(NTOK / 4), dim3(256), 0, stream,
                       x, grad, rW, rb, probs, t2i, t2g, counts);
    hipLaunchKernelGGL(offsets_kernel, dim3(1), dim3(64), 0, stream, counts, offsets, cursor);
    hipLaunchKernelGGL(build_lists, dim3(NTOK / 256), dim3(256), 0, stream,
                       t2i, t2g, cursor, tok, gate, tslot);
    hipLaunchKernelGGL(gather_kernel, dim3(2 * NTOK), dim3(256), 0, stream, x, tok, Xg);
    hipLaunchKernelGGL(transpose_cast2, dim3(1024, 16), dim3(256), 0, stream,
                       W1, W2, W1t, W2t);

    // GEMM1: ragged [counts, 4096] = Xg @ W1t^T, gelu -> Hbuf (bf16, packed rows)
    hipLaunchKernelGGL((moe_gemm8<DDIM, 0>), dim3((HDIM / 256) * 64 * NEXP), dim3(512), 0,
                       stream, Xg, W1t, b1, Hbuf, (float*)nullptr, counts, offsets, gate,
                       HDIM / 256);
    // GEMM2: Yg[slot] = gate * (Hbuf @ W2t^T + b2)   (fp32, no atomics)
    hipLaunchKernelGGL((moe_gemm8<HDIM, 1>), dim3((DDIM / 256) * 64 * NEXP), dim3(512), 0,
                       stream, Hbuf, W2t, b2, (bf16_t*)nullptr, Yg, counts, offsets, gate,
                       DDIM / 256);
    hipLaunchKernelGGL(combine_kernel, dim3(NTOK), dim3(256), 0, stream, Yg, tslot, out);
}